// Round 1
// baseline (553.687 us; speedup 1.0000x reference)
//
#include <hip/hip_runtime.h>
#include <math.h>

#define S_LEN 2048
#define DMODEL 512
#define NHEAD 8
#define DHEAD 64
#define LN_EPS 1e-5f

// ---------------- wave helpers (wave64) ----------------
__device__ __forceinline__ float wave_reduce_sum(float x) {
#pragma unroll
  for (int off = 32; off > 0; off >>= 1) x += __shfl_xor(x, off);
  return x;
}
__device__ __forceinline__ float wave_reduce_max(float x) {
#pragma unroll
  for (int off = 32; off > 0; off >>= 1) x = fmaxf(x, __shfl_xor(x, off));
  return x;
}

// ---------------- LayerNorm: one block per row ----------------
__global__ __launch_bounds__(256) void ln_kernel(const float* __restrict__ x,
                                                 const float* __restrict__ g,
                                                 const float* __restrict__ b,
                                                 float* __restrict__ xn) {
  const int row = blockIdx.x;
  const int tid = threadIdx.x;  // 256 threads, 2 elems each (D=512)
  const float2 v = ((const float2*)(x + (size_t)row * DMODEL))[tid];
  float s = v.x + v.y;
  float s2 = v.x * v.x + v.y * v.y;
  s = wave_reduce_sum(s);
  s2 = wave_reduce_sum(s2);
  __shared__ float red[2][4];
  const int wv = tid >> 6, ln = tid & 63;
  if (ln == 0) { red[0][wv] = s; red[1][wv] = s2; }
  __syncthreads();
  s = red[0][0] + red[0][1] + red[0][2] + red[0][3];
  s2 = red[1][0] + red[1][1] + red[1][2] + red[1][3];
  const float mu = s * (1.0f / DMODEL);
  const float var = s2 * (1.0f / DMODEL) - mu * mu;  // biased var, matches jnp.mean
  const float rs = rsqrtf(var + LN_EPS);
  const float2 gg = ((const float2*)g)[tid];
  const float2 bb = ((const float2*)b)[tid];
  float2 o;
  o.x = (v.x - mu) * rs * gg.x + bb.x;
  o.y = (v.y - mu) * rs * gg.y + bb.y;
  ((float2*)(xn + (size_t)row * DMODEL))[tid] = o;
}

// ---------------- fp32 tiled GEMM: C = A[M,K] @ B[K,N] + bias (+fuse) -------
// FUSE: 0 = bias only, 1 = bias + exact GELU, 2 = bias + residual add
// BM=128, BN=64, BK=16, 256 threads, 8x4 micro-tile. All dims divide evenly.
template <int FUSE>
__global__ __launch_bounds__(256) void gemm_kernel(const float* __restrict__ A,
                                                   const float* __restrict__ B,
                                                   const float* __restrict__ bias,
                                                   const float* __restrict__ res,
                                                   float* __restrict__ C,
                                                   int M, int N, int K) {
  const int BK = 16;
  __shared__ float As[16][132];  // [k][m], stride 132 keeps float4-aligned rows
  __shared__ float Bs[16][68];   // [k][n]
  const int tid = threadIdx.x;
  const int tx = tid & 15;   // n-dir, 16 cols of 4
  const int ty = tid >> 4;   // m-dir, 16 rows of 8
  const int rowBase = blockIdx.y * 128;
  const int colBase = blockIdx.x * 64;

  float acc[8][4] = {};

  for (int kk = 0; kk < K; kk += BK) {
    // A tile: 128x16 = 512 float4, 2 per thread, store transposed
#pragma unroll
    for (int r = 0; r < 2; r++) {
      const int idx = tid + r * 256;
      const int m = idx >> 2;
      const int kq = (idx & 3) * 4;
      const float4 av = *(const float4*)(A + (size_t)(rowBase + m) * K + kk + kq);
      As[kq + 0][m] = av.x;
      As[kq + 1][m] = av.y;
      As[kq + 2][m] = av.z;
      As[kq + 3][m] = av.w;
    }
    // B tile: 16x64 = 256 float4, 1 per thread
    {
      const int k = tid >> 4;
      const int nq = (tid & 15) * 4;
      *(float4*)&Bs[k][nq] =
          *(const float4*)(B + (size_t)(kk + k) * N + colBase + nq);
    }
    __syncthreads();
#pragma unroll
    for (int k = 0; k < BK; k++) {
      const float4 a0 = *(const float4*)&As[k][ty * 8];
      const float4 a1 = *(const float4*)&As[k][ty * 8 + 4];
      const float4 bv = *(const float4*)&Bs[k][tx * 4];
      const float am[8] = {a0.x, a0.y, a0.z, a0.w, a1.x, a1.y, a1.z, a1.w};
      const float bn[4] = {bv.x, bv.y, bv.z, bv.w};
#pragma unroll
      for (int i = 0; i < 8; i++)
#pragma unroll
        for (int j = 0; j < 4; j++) acc[i][j] = fmaf(am[i], bn[j], acc[i][j]);
    }
    __syncthreads();
  }

  const int col = colBase + tx * 4;
  const float4 bs = *(const float4*)(bias + col);
#pragma unroll
  for (int i = 0; i < 8; i++) {
    const int row = rowBase + ty * 8 + i;
    float4 o;
    o.x = acc[i][0] + bs.x;
    o.y = acc[i][1] + bs.y;
    o.z = acc[i][2] + bs.z;
    o.w = acc[i][3] + bs.w;
    if (FUSE == 1) {  // exact GELU
      o.x = 0.5f * o.x * (1.0f + erff(o.x * 0.70710678118654752f));
      o.y = 0.5f * o.y * (1.0f + erff(o.y * 0.70710678118654752f));
      o.z = 0.5f * o.z * (1.0f + erff(o.z * 0.70710678118654752f));
      o.w = 0.5f * o.w * (1.0f + erff(o.w * 0.70710678118654752f));
    } else if (FUSE == 2) {
      const float4 rv = *(const float4*)(res + (size_t)row * N + col);
      o.x += rv.x; o.y += rv.y; o.z += rv.z; o.w += rv.w;
    }
    *(float4*)(C + (size_t)row * N + col) = o;
  }
}

// ---------------- local attention: one wave per (head, query) ----------------
// qkv layout: [s][1536] with q at c, k at 512+c, v at 1024+c, c = h*64+d.
// Reference pads K/V with ZEROS and does NOT mask: out-of-range positions
// have score exactly 0 and participate in softmax; their V contribution is 0.
__global__ __launch_bounds__(256) void attn_kernel(const float* __restrict__ qkv,
                                                   float* __restrict__ attn) {
  const int w = blockIdx.x * 4 + (threadIdx.x >> 6);  // 16384 waves
  const int lane = threadIdx.x & 63;
  const int h = w >> 11;       // w / 2048
  const int s = w & 2047;      // w % 2048
  const int hc = h * DHEAD;

  const float qv = qkv[(size_t)s * 1536 + hc + lane];

  // scores: lane handles window j=lane (sc0) and j=64+lane (sc1); j=128 -> sc2
  const int pos0 = s - 64 + lane;  // j = lane
  const int pos1 = s + lane;       // j = 64 + lane
  const float m0 = (pos0 >= 0) ? 1.0f : 0.0f;
  const float m1 = (pos1 < S_LEN) ? 1.0f : 0.0f;
  const int cp0 = max(pos0, 0);
  const int cp1 = min(pos1, S_LEN - 1);
  const float* k0 = qkv + (size_t)cp0 * 1536 + 512 + hc;
  const float* k1 = qkv + (size_t)cp1 * 1536 + 512 + hc;
  float sc0 = 0.f, sc1 = 0.f;
#pragma unroll 8
  for (int d = 0; d < 64; d++) {
    const float qd = __shfl(qv, d);
    sc0 = fmaf(qd, k0[d], sc0);
    sc1 = fmaf(qd, k1[d], sc1);
  }
  sc0 = sc0 * 0.125f * m0;  // invalid -> exactly 0 (zero-padded key)
  sc1 = sc1 * 0.125f * m1;

  // j = 128: pos = s+64, dot via lane-parallel partials
  const int pos2 = s + 64;
  const float m2 = (pos2 < S_LEN) ? 1.0f : 0.0f;
  const int cp2 = min(pos2, S_LEN - 1);
  const float p2 = qv * qkv[(size_t)cp2 * 1536 + 512 + hc + lane];
  const float sc2 = wave_reduce_sum(p2) * 0.125f * m2;

  const float mx = fmaxf(wave_reduce_max(fmaxf(sc0, sc1)), sc2);
  const float e0 = __expf(sc0 - mx);
  const float e1 = __expf(sc1 - mx);
  const float e2 = __expf(sc2 - mx);
  const float denom = wave_reduce_sum(e0 + e1) + e2;  // all 129 terms

  // PV: out[d=lane] = sum_j w_j * V[pos_j][lane]  (coalesced V loads)
  const float* Vb = qkv + 1024 + hc + lane;
  float acc = 0.f;
#pragma unroll 8
  for (int jj = 0; jj < 64; jj++) {
    const float w0 = __shfl(e0, jj);
    const float w1 = __shfl(e1, jj);
    const int p0 = s - 64 + jj;   // wave-uniform bounds checks
    const int p1 = s + jj;
    const float v0 = (p0 >= 0) ? Vb[(size_t)p0 * 1536] : 0.f;
    const float v1 = (p1 < S_LEN) ? Vb[(size_t)p1 * 1536] : 0.f;
    acc = fmaf(w0, v0, acc);
    acc = fmaf(w1, v1, acc);
  }
  acc = fmaf(e2, (pos2 < S_LEN) ? Vb[(size_t)pos2 * 1536] : 0.f, acc);

  attn[(size_t)s * DMODEL + hc + lane] = acc / denom;
}

// ---------------- launch ----------------
extern "C" void kernel_launch(void* const* d_in, const int* in_sizes, int n_in,
                              void* d_out, int out_size, void* d_ws, size_t ws_size,
                              hipStream_t stream) {
  const float* x     = (const float*)d_in[0];
  const float* w_qkv = (const float*)d_in[1];
  const float* b_qkv = (const float*)d_in[2];
  const float* w_out = (const float*)d_in[3];
  const float* b_out = (const float*)d_in[4];
  const float* ln_g  = (const float*)d_in[5];
  const float* ln_b  = (const float*)d_in[6];
  const float* w1    = (const float*)d_in[7];
  const float* b1    = (const float*)d_in[8];
  const float* w2    = (const float*)d_in[9];
  const float* b2    = (const float*)d_in[10];
  float* out = (float*)d_out;

  float* ws = (float*)d_ws;
  float* xn   = ws;                          // 1M floats (4 MB)
  float* qkv  = ws + (1u << 20);             // 3M floats (12 MB)
  float* attn = ws;                          // reuse xn region (dead after QKV)
  float* h1   = ws + (4u << 20);             // 4M floats (16 MB); total 32 MB

  // 1. LayerNorm
  ln_kernel<<<S_LEN, 256, 0, stream>>>(x, ln_g, ln_b, xn);
  // 2. QKV GEMM: [2048,512]@[512,1536]
  gemm_kernel<0><<<dim3(1536 / 64, 2048 / 128), 256, 0, stream>>>(
      xn, w_qkv, b_qkv, nullptr, qkv, S_LEN, 3 * DMODEL, DMODEL);
  // 3. local attention
  attn_kernel<<<(S_LEN * NHEAD) / 4, 256, 0, stream>>>(qkv, attn);
  // 4. out-proj + residual(x): [2048,512]@[512,512] + x
  gemm_kernel<2><<<dim3(512 / 64, 2048 / 128), 256, 0, stream>>>(
      attn, w_out, b_out, x, out, S_LEN, DMODEL, DMODEL);
  // 5. FFN1 + GELU: [2048,512]@[512,2048]
  gemm_kernel<1><<<dim3(2048 / 64, 2048 / 128), 256, 0, stream>>>(
      out, w1, b1, nullptr, h1, S_LEN, 4 * DMODEL, DMODEL);
  // 6. FFN2 + residual(out): [2048,2048]@[2048,512] + out  (in-place safe)
  gemm_kernel<2><<<dim3(512 / 64, 2048 / 128), 256, 0, stream>>>(
      h1, w2, b2, out, out, S_LEN, DMODEL, 4 * DMODEL);
}

// Round 2
// 291.121 us; speedup vs baseline: 1.9019x; 1.9019x over previous
//
#include <hip/hip_runtime.h>
#include <math.h>

#define S_LEN 2048
#define DMODEL 512
#define NHEAD 8
#define DHEAD 64
#define LN_EPS 1e-5f

typedef __bf16 bf16;
typedef __bf16 bf16x8 __attribute__((ext_vector_type(8)));
typedef __bf16 bf16x2 __attribute__((ext_vector_type(2)));
typedef float f32x4 __attribute__((ext_vector_type(4)));

// ---------------- wave helpers (wave64) ----------------
__device__ __forceinline__ float wave_reduce_sum(float x) {
#pragma unroll
  for (int off = 32; off > 0; off >>= 1) x += __shfl_xor(x, off);
  return x;
}
__device__ __forceinline__ float wave_reduce_max(float x) {
#pragma unroll
  for (int off = 32; off > 0; off >>= 1) x = fmaxf(x, __shfl_xor(x, off));
  return x;
}

// ---------------- LayerNorm: one block per row, bf16 output ----------------
__global__ __launch_bounds__(256) void ln_kernel(const float* __restrict__ x,
                                                 const float* __restrict__ g,
                                                 const float* __restrict__ b,
                                                 bf16* __restrict__ xn) {
  const int row = blockIdx.x;
  const int tid = threadIdx.x;  // 256 threads, 2 elems each (D=512)
  const float2 v = ((const float2*)(x + (size_t)row * DMODEL))[tid];
  float s = v.x + v.y;
  float s2 = v.x * v.x + v.y * v.y;
  s = wave_reduce_sum(s);
  s2 = wave_reduce_sum(s2);
  __shared__ float red[2][4];
  const int wv = tid >> 6, ln = tid & 63;
  if (ln == 0) { red[0][wv] = s; red[1][wv] = s2; }
  __syncthreads();
  s = red[0][0] + red[0][1] + red[0][2] + red[0][3];
  s2 = red[1][0] + red[1][1] + red[1][2] + red[1][3];
  const float mu = s * (1.0f / DMODEL);
  const float var = s2 * (1.0f / DMODEL) - mu * mu;  // biased var
  const float rs = rsqrtf(var + LN_EPS);
  const float2 gg = ((const float2*)g)[tid];
  const float2 bb = ((const float2*)b)[tid];
  bf16x2 o;
  o[0] = (bf16)((v.x - mu) * rs * gg.x + bb.x);
  o[1] = (bf16)((v.y - mu) * rs * gg.y + bb.y);
  ((bf16x2*)(xn + (size_t)row * DMODEL))[tid] = o;
}

// ---------------- cast+transpose: W[K][N] fp32 -> WT[N][K] bf16 ----------------
__global__ __launch_bounds__(256) void transpose_cast(const float* __restrict__ W,
                                                      bf16* __restrict__ WT,
                                                      int K, int N) {
  __shared__ float t[32][33];
  const int c = threadIdx.x & 31, r8 = threadIdx.x >> 5;
  const int n0 = blockIdx.x * 32, k0 = blockIdx.y * 32;
#pragma unroll
  for (int it = 0; it < 4; it++) {
    const int r = r8 + it * 8;
    t[r][c] = W[(size_t)(k0 + r) * N + n0 + c];
  }
  __syncthreads();
#pragma unroll
  for (int it = 0; it < 4; it++) {
    const int r = r8 + it * 8;
    WT[(size_t)(n0 + r) * K + k0 + c] = (bf16)t[c][r];
  }
}

// ---------------- bf16 MFMA GEMM: C = A[M,K] @ BT[N,K]^T + bias (+fuse) -----
// m97 structure: 128x128 tile, BK=32, 4 waves, 4x4 of 16x16x32 MFMA each,
// global_load_lds width-16 staging.
// MODE: 0 = bias -> f32 out
//       1 = bias + residual(f32) -> f32 out AND bf16 out
//       2 = bias + exact GELU -> bf16 out
//       3 = bias + residual(f32) -> f32 out
template <int MODE>
__global__ __launch_bounds__(256) void mm_kernel(const bf16* __restrict__ A,
                                                 const bf16* __restrict__ BT,
                                                 const float* __restrict__ bias,
                                                 const float* __restrict__ res,
                                                 float* __restrict__ Cf,
                                                 bf16* __restrict__ Cb,
                                                 int N, int K) {
  __shared__ bf16 As[128 * 32];
  __shared__ bf16 Bs[128 * 32];
  const int tid = threadIdx.x;
  const int wave = tid >> 6, lane = tid & 63;
  const int rowBase = blockIdx.y * 128, colBase = blockIdx.x * 128;
  const int lr = lane & 15, kg = lane >> 4;
  const int wm = wave & 1, wn = wave >> 1;

  f32x4 acc[4][4] = {};

  // staging geometry: 8 segments of 16 rows; wave wv stages segments 2wv,2wv+1
  const int srow = lane >> 2;        // 0..15
  const int skcol = (lane & 3) * 8;  // 0,8,16,24

  for (int kk = 0; kk < K; kk += 32) {
#pragma unroll
    for (int it = 0; it < 2; it++) {
      const int seg = wave * 2 + it;
      const int row = seg * 16 + srow;
      const bf16* ga = A + (size_t)(rowBase + row) * K + kk + skcol;
      const bf16* gb = BT + (size_t)(colBase + row) * K + kk + skcol;
      __builtin_amdgcn_global_load_lds(
          (const __attribute__((address_space(1))) void*)ga,
          (__attribute__((address_space(3))) void*)(As + seg * 512), 16, 0, 0);
      __builtin_amdgcn_global_load_lds(
          (const __attribute__((address_space(1))) void*)gb,
          (__attribute__((address_space(3))) void*)(Bs + seg * 512), 16, 0, 0);
    }
    __syncthreads();

    bf16x8 af[4], bfr[4];
#pragma unroll
    for (int i = 0; i < 4; i++)
      af[i] = *(const bf16x8*)(As + ((wm * 64 + i * 16 + lr) * 32 + kg * 8));
#pragma unroll
    for (int j = 0; j < 4; j++)
      bfr[j] = *(const bf16x8*)(Bs + ((wn * 64 + j * 16 + lr) * 32 + kg * 8));
#pragma unroll
    for (int i = 0; i < 4; i++)
#pragma unroll
      for (int j = 0; j < 4; j++)
        acc[i][j] = __builtin_amdgcn_mfma_f32_16x16x32_bf16(af[i], bfr[j],
                                                            acc[i][j], 0, 0, 0);
    __syncthreads();
  }

  // epilogue: C/D map col=lane&15, row=(lane>>4)*4+reg
  const int orow0 = rowBase + wm * 64 + (lane >> 4) * 4;
  const int ocol0 = colBase + wn * 64 + lr;
#pragma unroll
  for (int j = 0; j < 4; j++) {
    const int col = ocol0 + j * 16;
    const float bs = bias[col];
#pragma unroll
    for (int i = 0; i < 4; i++) {
#pragma unroll
      for (int r = 0; r < 4; r++) {
        const int row = orow0 + i * 16 + r;
        float v = acc[i][j][r] + bs;
        if (MODE == 2) v = 0.5f * v * (1.0f + erff(v * 0.70710678118654752f));
        if (MODE == 1 || MODE == 3) v += res[(size_t)row * N + col];
        if (MODE != 2) Cf[(size_t)row * N + col] = v;
        if (MODE == 1 || MODE == 2) Cb[(size_t)row * N + col] = (bf16)v;
      }
    }
  }
}

// ---------------- local attention: one wave per (head, query) ----------------
// qkv fp32 [s][1536]: q at c, k at 512+c, v at 1024+c, c = h*64+d.
// Reference zero-pads K/V, does NOT mask: OOR scores are exactly 0 and
// participate in softmax; padded V contributes 0.
__global__ __launch_bounds__(256) void attn_kernel(const float* __restrict__ qkv,
                                                   bf16* __restrict__ attn) {
  const int w = blockIdx.x * 4 + (threadIdx.x >> 6);
  const int lane = threadIdx.x & 63;
  const int h = w >> 11;
  const int s = w & 2047;
  const int hc = h * DHEAD;

  const float qv = qkv[(size_t)s * 1536 + hc + lane];

  const int pos0 = s - 64 + lane;
  const int pos1 = s + lane;
  const float m0 = (pos0 >= 0) ? 1.0f : 0.0f;
  const float m1 = (pos1 < S_LEN) ? 1.0f : 0.0f;
  const int cp0 = max(pos0, 0);
  const int cp1 = min(pos1, S_LEN - 1);
  const float* k0 = qkv + (size_t)cp0 * 1536 + 512 + hc;
  const float* k1 = qkv + (size_t)cp1 * 1536 + 512 + hc;
  float sc0 = 0.f, sc1 = 0.f;
#pragma unroll 8
  for (int d = 0; d < 64; d++) {
    const float qd = __shfl(qv, d);
    sc0 = fmaf(qd, k0[d], sc0);
    sc1 = fmaf(qd, k1[d], sc1);
  }
  sc0 = sc0 * 0.125f * m0;
  sc1 = sc1 * 0.125f * m1;

  const int pos2 = s + 64;
  const float m2 = (pos2 < S_LEN) ? 1.0f : 0.0f;
  const int cp2 = min(pos2, S_LEN - 1);
  const float p2 = qv * qkv[(size_t)cp2 * 1536 + 512 + hc + lane];
  const float sc2 = wave_reduce_sum(p2) * 0.125f * m2;

  const float mx = fmaxf(wave_reduce_max(fmaxf(sc0, sc1)), sc2);
  const float e0 = __expf(sc0 - mx);
  const float e1 = __expf(sc1 - mx);
  const float e2 = __expf(sc2 - mx);
  const float denom = wave_reduce_sum(e0 + e1) + e2;

  const float* Vb = qkv + 1024 + hc + lane;
  float acc = 0.f;
#pragma unroll 8
  for (int jj = 0; jj < 64; jj++) {
    const float w0 = __shfl(e0, jj);
    const float w1 = __shfl(e1, jj);
    const int p0 = s - 64 + jj;
    const int p1 = s + jj;
    const float v0 = (p0 >= 0) ? Vb[(size_t)p0 * 1536] : 0.f;
    const float v1 = (p1 < S_LEN) ? Vb[(size_t)p1 * 1536] : 0.f;
    acc = fmaf(w0, v0, acc);
    acc = fmaf(w1, v1, acc);
  }
  acc = fmaf(e2, (pos2 < S_LEN) ? Vb[(size_t)pos2 * 1536] : 0.f, acc);

  attn[(size_t)s * DMODEL + hc + lane] = (bf16)(acc / denom);
}

// ---------------- launch ----------------
extern "C" void kernel_launch(void* const* d_in, const int* in_sizes, int n_in,
                              void* d_out, int out_size, void* d_ws, size_t ws_size,
                              hipStream_t stream) {
  const float* x     = (const float*)d_in[0];
  const float* w_qkv = (const float*)d_in[1];
  const float* b_qkv = (const float*)d_in[2];
  const float* w_out = (const float*)d_in[3];
  const float* b_out = (const float*)d_in[4];
  const float* ln_g  = (const float*)d_in[5];
  const float* ln_b  = (const float*)d_in[6];
  const float* w1    = (const float*)d_in[7];
  const float* b1    = (const float*)d_in[8];
  const float* w2    = (const float*)d_in[9];
  const float* b2    = (const float*)d_in[10];
  float* out = (float*)d_out;

  char* w = (char*)d_ws;
  const size_t MB = 1u << 20;
  bf16*  xn    = (bf16*)(w + 0);          // 2 MB [0,2)
  bf16*  attnb = (bf16*)(w + 0);          // alias xn (dead after QKV gemm)
  float* qkv   = (float*)(w + 2 * MB);    // 12 MB [2,14)
  bf16*  outb  = (bf16*)(w + 2 * MB);     // alias qkv (dead after attention)
  bf16*  h1    = (bf16*)(w + 4 * MB);     // 8 MB [4,12)
  bf16*  wqkvT = (bf16*)(w + 14 * MB);    // 1.5 MB
  bf16*  woutT = (bf16*)(w + 15 * MB + 512 * 1024);  // 0.5 MB
  bf16*  w1T   = (bf16*)(w + 16 * MB);    // 2 MB
  bf16*  w2T   = (bf16*)(w + 18 * MB);    // 2 MB

  // weight cast+transpose (every call; ~3M elems total)
  transpose_cast<<<dim3(1536 / 32, 512 / 32), 256, 0, stream>>>(w_qkv, wqkvT, 512, 1536);
  transpose_cast<<<dim3(512 / 32, 512 / 32), 256, 0, stream>>>(w_out, woutT, 512, 512);
  transpose_cast<<<dim3(2048 / 32, 512 / 32), 256, 0, stream>>>(w1, w1T, 512, 2048);
  transpose_cast<<<dim3(512 / 32, 2048 / 32), 256, 0, stream>>>(w2, w2T, 2048, 512);

  // 1. LayerNorm -> bf16
  ln_kernel<<<S_LEN, 256, 0, stream>>>(x, ln_g, ln_b, xn);
  // 2. QKV: [2048,512] @ [512,1536] -> fp32 qkv
  mm_kernel<0><<<dim3(1536 / 128, S_LEN / 128), 256, 0, stream>>>(
      xn, wqkvT, b_qkv, nullptr, qkv, nullptr, 1536, 512);
  // 3. local attention -> bf16 attn
  attn_kernel<<<(S_LEN * NHEAD) / 4, 256, 0, stream>>>(qkv, attnb);
  // 4. out-proj + residual(x) -> f32 d_out AND bf16 outb
  mm_kernel<1><<<dim3(512 / 128, S_LEN / 128), 256, 0, stream>>>(
      attnb, woutT, b_out, x, out, outb, 512, 512);
  // 5. FFN1 + GELU -> bf16 h1
  mm_kernel<2><<<dim3(2048 / 128, S_LEN / 128), 256, 0, stream>>>(
      outb, w1T, b1, nullptr, nullptr, h1, 2048, 512);
  // 6. FFN2 + residual(out) -> f32 d_out (in-place safe: 1 read, 1 write/elem)
  mm_kernel<3><<<dim3(512 / 128, S_LEN / 128), 256, 0, stream>>>(
      h1, w2T, b2, out, out, nullptr, 512, 2048);
}

// Round 3
// 174.314 us; speedup vs baseline: 3.1764x; 1.6701x over previous
//
#include <hip/hip_runtime.h>
#include <math.h>

#define S_LEN 2048
#define DMODEL 512
#define NHEAD 8
#define DHEAD 64
#define LN_EPS 1e-5f

typedef __bf16 bf16;
typedef __bf16 bf16x8 __attribute__((ext_vector_type(8)));
typedef __bf16 bf16x2 __attribute__((ext_vector_type(2)));
typedef float f32x4 __attribute__((ext_vector_type(4)));

// ---------------- wave helpers (wave64) ----------------
__device__ __forceinline__ float wave_reduce_sum(float x) {
#pragma unroll
  for (int off = 32; off > 0; off >>= 1) x += __shfl_xor(x, off);
  return x;
}

// ---------------- LayerNorm: one block per row, bf16 output ----------------
__global__ __launch_bounds__(256) void ln_kernel(const float* __restrict__ x,
                                                 const float* __restrict__ g,
                                                 const float* __restrict__ b,
                                                 bf16* __restrict__ xn) {
  const int row = blockIdx.x;
  const int tid = threadIdx.x;
  const float2 v = ((const float2*)(x + (size_t)row * DMODEL))[tid];
  float s = v.x + v.y;
  float s2 = v.x * v.x + v.y * v.y;
  s = wave_reduce_sum(s);
  s2 = wave_reduce_sum(s2);
  __shared__ float red[2][4];
  const int wv = tid >> 6, ln = tid & 63;
  if (ln == 0) { red[0][wv] = s; red[1][wv] = s2; }
  __syncthreads();
  s = red[0][0] + red[0][1] + red[0][2] + red[0][3];
  s2 = red[1][0] + red[1][1] + red[1][2] + red[1][3];
  const float mu = s * (1.0f / DMODEL);
  const float var = s2 * (1.0f / DMODEL) - mu * mu;
  const float rs = rsqrtf(var + LN_EPS);
  const float2 gg = ((const float2*)g)[tid];
  const float2 bb = ((const float2*)b)[tid];
  bf16x2 o;
  o[0] = (bf16)((v.x - mu) * rs * gg.x + bb.x);
  o[1] = (bf16)((v.y - mu) * rs * gg.y + bb.y);
  ((bf16x2*)(xn + (size_t)row * DMODEL))[tid] = o;
}

// ---------------- cast+transpose: W[K][N] fp32 -> WT[N][K] bf16 -------------
__global__ __launch_bounds__(256) void transpose_cast(const float* __restrict__ W,
                                                      bf16* __restrict__ WT,
                                                      int K, int N) {
  __shared__ float t[32][33];
  const int c = threadIdx.x & 31, r8 = threadIdx.x >> 5;
  const int n0 = blockIdx.x * 32, k0 = blockIdx.y * 32;
#pragma unroll
  for (int it = 0; it < 4; it++) {
    const int r = r8 + it * 8;
    t[r][c] = W[(size_t)(k0 + r) * N + n0 + c];
  }
  __syncthreads();
#pragma unroll
  for (int it = 0; it < 4; it++) {
    const int r = r8 + it * 8;
    WT[(size_t)(n0 + r) * K + k0 + c] = (bf16)t[c][r];
  }
}

// ---- V transpose: qkvb v-part [s][hc+d] -> vT[(hc+d)][s], bf16 -------------
__global__ __launch_bounds__(256) void v_transpose(const bf16* __restrict__ qkvb,
                                                   bf16* __restrict__ vT) {
  __shared__ bf16 t[32][33];
  const int c = threadIdx.x & 31, r8 = threadIdx.x >> 5;
  const int c0 = blockIdx.x * 32;  // channel 0..511
  const int s0 = blockIdx.y * 32;  // seq
#pragma unroll
  for (int it = 0; it < 4; it++) {
    const int r = r8 + it * 8;
    t[r][c] = qkvb[(size_t)(s0 + r) * 1536 + 1024 + c0 + c];
  }
  __syncthreads();
#pragma unroll
  for (int it = 0; it < 4; it++) {
    const int r = r8 + it * 8;
    vT[(size_t)(c0 + r) * S_LEN + s0 + c] = t[c][r];
  }
}

// ------------- shared epilogue math -----------------------------------------
// MODE: 0 = bias -> bf16 out
//       1 = bias + residual(f32) -> f32 out AND bf16 out
//       2 = bias + exact GELU -> bf16 out
//       3 = bias + residual(f32) -> f32 out
template <int MODE>
__device__ __forceinline__ void epilogue_store(float v, const float* res,
                                               float* Cf, bf16* Cb,
                                               size_t row, size_t col, int N) {
  if (MODE == 2) v = 0.5f * v * (1.0f + erff(v * 0.70710678118654752f));
  if (MODE == 1 || MODE == 3) v += res[row * N + col];
  if (MODE == 1 || MODE == 3) Cf[row * N + col] = v;
  if (MODE == 0 || MODE == 1 || MODE == 2) Cb[row * N + col] = (bf16)v;
}

// ---------------- bf16 MFMA GEMM, 128x128 tile ------------------------------
template <int MODE>
__global__ __launch_bounds__(256) void mm_kernel(const bf16* __restrict__ A,
                                                 const bf16* __restrict__ BT,
                                                 const float* __restrict__ bias,
                                                 const float* __restrict__ res,
                                                 float* __restrict__ Cf,
                                                 bf16* __restrict__ Cb,
                                                 int N, int K) {
  __shared__ bf16 As[128 * 32];
  __shared__ bf16 Bs[128 * 32];
  const int tid = threadIdx.x;
  const int wave = tid >> 6, lane = tid & 63;
  const int rowBase = blockIdx.y * 128, colBase = blockIdx.x * 128;
  const int lr = lane & 15, kg = lane >> 4;
  const int wm = wave & 1, wn = wave >> 1;

  f32x4 acc[4][4] = {};
  const int srow = lane >> 2;
  const int skcol = (lane & 3) * 8;

  for (int kk = 0; kk < K; kk += 32) {
#pragma unroll
    for (int it = 0; it < 2; it++) {
      const int seg = wave * 2 + it;
      const int row = seg * 16 + srow;
      const bf16* ga = A + (size_t)(rowBase + row) * K + kk + skcol;
      const bf16* gb = BT + (size_t)(colBase + row) * K + kk + skcol;
      __builtin_amdgcn_global_load_lds(
          (const __attribute__((address_space(1))) void*)ga,
          (__attribute__((address_space(3))) void*)(As + seg * 512), 16, 0, 0);
      __builtin_amdgcn_global_load_lds(
          (const __attribute__((address_space(1))) void*)gb,
          (__attribute__((address_space(3))) void*)(Bs + seg * 512), 16, 0, 0);
    }
    __syncthreads();

    bf16x8 af[4], bfr[4];
#pragma unroll
    for (int i = 0; i < 4; i++)
      af[i] = *(const bf16x8*)(As + ((wm * 64 + i * 16 + lr) * 32 + kg * 8));
#pragma unroll
    for (int j = 0; j < 4; j++)
      bfr[j] = *(const bf16x8*)(Bs + ((wn * 64 + j * 16 + lr) * 32 + kg * 8));
#pragma unroll
    for (int i = 0; i < 4; i++)
#pragma unroll
      for (int j = 0; j < 4; j++)
        acc[i][j] = __builtin_amdgcn_mfma_f32_16x16x32_bf16(af[i], bfr[j],
                                                            acc[i][j], 0, 0, 0);
    __syncthreads();
  }

  const int orow0 = rowBase + wm * 64 + kg * 4;
  const int ocol0 = colBase + wn * 64 + lr;
#pragma unroll
  for (int j = 0; j < 4; j++) {
    const int col = ocol0 + j * 16;
    const float bs = bias[col];
#pragma unroll
    for (int i = 0; i < 4; i++)
#pragma unroll
      for (int r = 0; r < 4; r++)
        epilogue_store<MODE>(acc[i][j][r] + bs, res, Cf, Cb,
                             (size_t)(orow0 + i * 16 + r), (size_t)col, N);
  }
}

// ---------------- bf16 MFMA GEMM, 64x64 tile (small-N shapes) ---------------
template <int MODE>
__global__ __launch_bounds__(256) void mm64_kernel(const bf16* __restrict__ A,
                                                   const bf16* __restrict__ BT,
                                                   const float* __restrict__ bias,
                                                   const float* __restrict__ res,
                                                   float* __restrict__ Cf,
                                                   bf16* __restrict__ Cb,
                                                   int N, int K) {
  __shared__ bf16 As[64 * 32];
  __shared__ bf16 Bs[64 * 32];
  const int tid = threadIdx.x;
  const int wave = tid >> 6, lane = tid & 63;
  const int rowBase = blockIdx.y * 64, colBase = blockIdx.x * 64;
  const int lr = lane & 15, kg = lane >> 4;
  const int wm = wave & 1, wn = wave >> 1;

  f32x4 acc[2][2] = {};
  const int srow = lane >> 2;
  const int skcol = (lane & 3) * 8;

  for (int kk = 0; kk < K; kk += 32) {
    const int row = wave * 16 + srow;
    const bf16* ga = A + (size_t)(rowBase + row) * K + kk + skcol;
    const bf16* gb = BT + (size_t)(colBase + row) * K + kk + skcol;
    __builtin_amdgcn_global_load_lds(
        (const __attribute__((address_space(1))) void*)ga,
        (__attribute__((address_space(3))) void*)(As + wave * 512), 16, 0, 0);
    __builtin_amdgcn_global_load_lds(
        (const __attribute__((address_space(1))) void*)gb,
        (__attribute__((address_space(3))) void*)(Bs + wave * 512), 16, 0, 0);
    __syncthreads();

    bf16x8 af[2], bfr[2];
#pragma unroll
    for (int i = 0; i < 2; i++)
      af[i] = *(const bf16x8*)(As + ((wm * 32 + i * 16 + lr) * 32 + kg * 8));
#pragma unroll
    for (int j = 0; j < 2; j++)
      bfr[j] = *(const bf16x8*)(Bs + ((wn * 32 + j * 16 + lr) * 32 + kg * 8));
#pragma unroll
    for (int i = 0; i < 2; i++)
#pragma unroll
      for (int j = 0; j < 2; j++)
        acc[i][j] = __builtin_amdgcn_mfma_f32_16x16x32_bf16(af[i], bfr[j],
                                                            acc[i][j], 0, 0, 0);
    __syncthreads();
  }

  const int orow0 = rowBase + wm * 32 + kg * 4;
  const int ocol0 = colBase + wn * 32 + lr;
#pragma unroll
  for (int j = 0; j < 2; j++) {
    const int col = ocol0 + j * 16;
    const float bs = bias[col];
#pragma unroll
    for (int i = 0; i < 2; i++)
#pragma unroll
      for (int r = 0; r < 4; r++)
        epilogue_store<MODE>(acc[i][j][r] + bs, res, Cf, Cb,
                             (size_t)(orow0 + i * 16 + r), (size_t)col, N);
  }
}

// ---------------- fused MFMA local attention --------------------------------
// Block = (query tile of 64, head). Stage K rows s0-64..s0+127 (192, OOR->0),
// Q tile, V^T into LDS (bf16). S = Q K^T via MFMA (band cols r in [q, q+128]
// per query q; OOR rows give score exactly 0 = reference zero-pad semantics).
// Register softmax over the band, P->LDS (A-layout), PV via MFMA.
__global__ __launch_bounds__(256) void attn_fused(const bf16* __restrict__ qkvb,
                                                  const bf16* __restrict__ vT,
                                                  bf16* __restrict__ attnb) {
  __shared__ bf16 Kl[192][72];  // reused as P[4][16][200] after QK^T
  __shared__ bf16 Vt[64][200];  // V^T: [d][r]
  __shared__ bf16 Ql[64][72];

  const int tid = threadIdx.x;
  const int s0 = blockIdx.x * 64;
  const int hc = blockIdx.y * DHEAD;

  // ---- stage Q (64x64) ----
  {
    const int row = tid >> 2, c0 = (tid & 3) * 16;
    const bf16* src = qkvb + (size_t)(s0 + row) * 1536 + hc + c0;
    *(bf16x8*)&Ql[row][c0] = *(const bf16x8*)src;
    *(bf16x8*)&Ql[row][c0 + 8] = *(const bf16x8*)(src + 8);
  }
  // ---- stage K (192x64), zero OOR rows ----
#pragma unroll
  for (int it = 0; it < 3; it++) {
    const int row = it * 64 + (tid >> 2), c0 = (tid & 3) * 16;
    const int p = s0 - 64 + row;
    bf16x8 a, b;
    if (p >= 0 && p < S_LEN) {
      const bf16* src = qkvb + (size_t)p * 1536 + 512 + hc + c0;
      a = *(const bf16x8*)src;
      b = *(const bf16x8*)(src + 8);
    } else {
#pragma unroll
      for (int j = 0; j < 8; j++) { a[j] = (bf16)0.f; b[j] = (bf16)0.f; }
    }
    *(bf16x8*)&Kl[row][c0] = a;
    *(bf16x8*)&Kl[row][c0 + 8] = b;
  }
  // ---- stage V^T (64 d x 192 r), zero OOR cols ----
  {
    const int d = tid >> 2, r0 = (tid & 3) * 48;
    const bf16* src = vT + (size_t)(hc + d) * S_LEN;
#pragma unroll
    for (int i = 0; i < 6; i++) {
      const int p0 = s0 - 64 + r0 + i * 8;
      bf16x8 v;
      if (p0 >= 0 && p0 + 8 <= S_LEN) {
        v = *(const bf16x8*)(src + p0);
      } else {
#pragma unroll
        for (int j = 0; j < 8; j++) {
          const int p = p0 + j;
          v[j] = (p >= 0 && p < S_LEN) ? src[p] : (bf16)0.f;
        }
      }
      *(bf16x8*)&Vt[d][r0 + i * 8] = v;
    }
  }
  __syncthreads();

  const int wv = tid >> 6, lane = tid & 63;
  const int lr = lane & 15, kg = lane >> 4;

  // ---- QK^T: stripe of 16 queries per wave, 12 col-tiles ----
  f32x4 c[12] = {};
#pragma unroll
  for (int step = 0; step < 2; step++) {
    const bf16x8 qf = *(const bf16x8*)&Ql[wv * 16 + lr][step * 32 + kg * 8];
#pragma unroll
    for (int t = 0; t < 12; t++) {
      const bf16x8 kf = *(const bf16x8*)&Kl[t * 16 + lr][step * 32 + kg * 8];
      c[t] = __builtin_amdgcn_mfma_f32_16x16x32_bf16(qf, kf, c[t], 0, 0, 0);
    }
  }

  // ---- banded softmax (C-layout: col=lr+16t, row q_local=kg*4+rr) ----
  float e[12][4];
  float inv[4];
#pragma unroll
  for (int rr = 0; rr < 4; rr++) {
    const int q = wv * 16 + kg * 4 + rr;
    float m = -1e30f;
#pragma unroll
    for (int t = 0; t < 12; t++) {
      const int col = t * 16 + lr;
      if (col >= q && col <= q + 128) m = fmaxf(m, c[t][rr] * 0.125f);
    }
#pragma unroll
    for (int off = 1; off < 16; off <<= 1) m = fmaxf(m, __shfl_xor(m, off));
    float sum = 0.f;
#pragma unroll
    for (int t = 0; t < 12; t++) {
      const int col = t * 16 + lr;
      const bool valid = (col >= q) && (col <= q + 128);
      const float ev = valid ? __expf(c[t][rr] * 0.125f - m) : 0.f;
      e[t][rr] = ev;
      sum += ev;
    }
#pragma unroll
    for (int off = 1; off < 16; off <<= 1) sum += __shfl_xor(sum, off);
    inv[rr] = 1.f / sum;
  }

  __syncthreads();  // all waves done reading Kl before overwriting with P

  // ---- write P (A-layout row-major [16][200] per stripe, overlays Kl) ----
  bf16* Pl = (bf16*)Kl + wv * (16 * 200);
#pragma unroll
  for (int rr = 0; rr < 4; rr++)
#pragma unroll
    for (int t = 0; t < 12; t++)
      Pl[(kg * 4 + rr) * 200 + t * 16 + lr] = (bf16)(e[t][rr] * inv[rr]);

  // ---- PV: [16][192] @ [192][64] (intra-wave P, no barrier needed) ----
  f32x4 o[4] = {};
#pragma unroll
  for (int step = 0; step < 6; step++) {
    const bf16x8 pf = *(const bf16x8*)&Pl[lr * 200 + step * 32 + kg * 8];
#pragma unroll
    for (int jt = 0; jt < 4; jt++) {
      const bf16x8 vf = *(const bf16x8*)&Vt[jt * 16 + lr][step * 32 + kg * 8];
      o[jt] = __builtin_amdgcn_mfma_f32_16x16x32_bf16(pf, vf, o[jt], 0, 0, 0);
    }
  }

  // ---- store: D-layout row = q_local = kg*4+rr, col d = jt*16+lr ----
#pragma unroll
  for (int jt = 0; jt < 4; jt++)
#pragma unroll
    for (int rr = 0; rr < 4; rr++) {
      const int q = wv * 16 + kg * 4 + rr;
      attnb[(size_t)(s0 + q) * DMODEL + hc + jt * 16 + lr] = (bf16)o[jt][rr];
    }
}

// ---------------- launch ----------------
extern "C" void kernel_launch(void* const* d_in, const int* in_sizes, int n_in,
                              void* d_out, int out_size, void* d_ws, size_t ws_size,
                              hipStream_t stream) {
  const float* x     = (const float*)d_in[0];
  const float* w_qkv = (const float*)d_in[1];
  const float* b_qkv = (const float*)d_in[2];
  const float* w_out = (const float*)d_in[3];
  const float* b_out = (const float*)d_in[4];
  const float* ln_g  = (const float*)d_in[5];
  const float* ln_b  = (const float*)d_in[6];
  const float* w1    = (const float*)d_in[7];
  const float* b1    = (const float*)d_in[8];
  const float* w2    = (const float*)d_in[9];
  const float* b2    = (const float*)d_in[10];
  float* out = (float*)d_out;

  char* w = (char*)d_ws;
  const size_t MB = 1u << 20;
  bf16* xn    = (bf16*)(w + 0);           // [0,2) MB
  bf16* attnb = (bf16*)(w + 0);           // alias xn (dead after QKV)
  bf16* qkvb  = (bf16*)(w + 2 * MB);      // [2,8) MB
  bf16* outb  = (bf16*)(w + 2 * MB);      // alias qkvb (dead after attention)
  bf16* vT    = (bf16*)(w + 8 * MB);      // [8,10) MB
  bf16* h1    = (bf16*)(w + 10 * MB);     // [10,18) MB
  bf16* wqkvT = (bf16*)(w + 18 * MB);     // 1.5 MB
  bf16* woutT = (bf16*)(w + 19 * MB + 512 * 1024);  // 0.5 MB
  bf16* w1T   = (bf16*)(w + 20 * MB);     // 2 MB
  bf16* w2T   = (bf16*)(w + 22 * MB);     // 2 MB

  transpose_cast<<<dim3(48, 16), 256, 0, stream>>>(w_qkv, wqkvT, 512, 1536);
  transpose_cast<<<dim3(16, 16), 256, 0, stream>>>(w_out, woutT, 512, 512);
  transpose_cast<<<dim3(64, 16), 256, 0, stream>>>(w1, w1T, 512, 2048);
  transpose_cast<<<dim3(16, 64), 256, 0, stream>>>(w2, w2T, 2048, 512);

  ln_kernel<<<S_LEN, 256, 0, stream>>>(x, ln_g, ln_b, xn);
  // QKV: [2048,512]@[512,1536] -> bf16
  mm_kernel<0><<<dim3(12, 16), 256, 0, stream>>>(xn, wqkvT, b_qkv, nullptr,
                                                 nullptr, qkvb, 1536, 512);
  v_transpose<<<dim3(16, 64), 256, 0, stream>>>(qkvb, vT);
  // fused attention
  attn_fused<<<dim3(32, 8), 256, 0, stream>>>(qkvb, vT, attnb);
  // out-proj + residual(x): f32 out + bf16 outb
  mm64_kernel<1><<<dim3(8, 32), 256, 0, stream>>>(attnb, woutT, b_out, x, out,
                                                  outb, 512, 512);
  // FFN1 + GELU -> bf16 h1
  mm_kernel<2><<<dim3(16, 16), 256, 0, stream>>>(outb, w1T, b1, nullptr,
                                                 nullptr, h1, 2048, 512);
  // FFN2 + residual(out) -> f32 out (in-place safe)
  mm64_kernel<3><<<dim3(8, 32), 256, 0, stream>>>(h1, w2T, b2, out, out,
                                                  nullptr, 512, 2048);
}

// Round 4
// 147.706 us; speedup vs baseline: 3.7486x; 1.1801x over previous
//
#include <hip/hip_runtime.h>
#include <math.h>

#define S_LEN 2048
#define DMODEL 512
#define NHEAD 8
#define DHEAD 64
#define LN_EPS 1e-5f

typedef __bf16 bf16;
typedef __bf16 bf16x8 __attribute__((ext_vector_type(8)));
typedef __bf16 bf16x2 __attribute__((ext_vector_type(2)));
typedef float f32x4 __attribute__((ext_vector_type(4)));

// ---------------- wave helpers (wave64) ----------------
__device__ __forceinline__ float wave_reduce_sum(float x) {
#pragma unroll
  for (int off = 32; off > 0; off >>= 1) x += __shfl_xor(x, off);
  return x;
}

// ---------------- LayerNorm: one block per row, bf16 output ----------------
__global__ __launch_bounds__(256) void ln_kernel(const float* __restrict__ x,
                                                 const float* __restrict__ g,
                                                 const float* __restrict__ b,
                                                 bf16* __restrict__ xn) {
  const int row = blockIdx.x;
  const int tid = threadIdx.x;
  const float2 v = ((const float2*)(x + (size_t)row * DMODEL))[tid];
  float s = v.x + v.y;
  float s2 = v.x * v.x + v.y * v.y;
  s = wave_reduce_sum(s);
  s2 = wave_reduce_sum(s2);
  __shared__ float red[2][4];
  const int wv = tid >> 6, ln = tid & 63;
  if (ln == 0) { red[0][wv] = s; red[1][wv] = s2; }
  __syncthreads();
  s = red[0][0] + red[0][1] + red[0][2] + red[0][3];
  s2 = red[1][0] + red[1][1] + red[1][2] + red[1][3];
  const float mu = s * (1.0f / DMODEL);
  const float var = s2 * (1.0f / DMODEL) - mu * mu;
  const float rs = rsqrtf(var + LN_EPS);
  const float2 gg = ((const float2*)g)[tid];
  const float2 bb = ((const float2*)b)[tid];
  bf16x2 o;
  o[0] = (bf16)((v.x - mu) * rs * gg.x + bb.x);
  o[1] = (bf16)((v.y - mu) * rs * gg.y + bb.y);
  ((bf16x2*)(xn + (size_t)row * DMODEL))[tid] = o;
}

// -------- combined weight cast+transpose: all 4 weights, one launch ---------
__global__ __launch_bounds__(256) void transpose_all(
    const float* __restrict__ w_qkv, const float* __restrict__ w_out,
    const float* __restrict__ w1, const float* __restrict__ w2,
    bf16* __restrict__ wqkvT, bf16* __restrict__ woutT,
    bf16* __restrict__ w1T, bf16* __restrict__ w2T) {
  int b = blockIdx.x;
  const float* W; bf16* WT; int K, N, bx, by;
  if (b < 768)       { W = w_qkv; WT = wqkvT; K = 512;  N = 1536; bx = b % 48; by = b / 48; }
  else if (b < 1024) { b -= 768;  W = w_out; WT = woutT; K = 512;  N = 512;  bx = b % 16; by = b / 16; }
  else if (b < 2048) { b -= 1024; W = w1;    WT = w1T;   K = 512;  N = 2048; bx = b % 64; by = b / 64; }
  else               { b -= 2048; W = w2;    WT = w2T;   K = 2048; N = 512;  bx = b % 16; by = b / 16; }
  __shared__ float t[32][33];
  const int c = threadIdx.x & 31, r8 = threadIdx.x >> 5;
  const int n0 = bx * 32, k0 = by * 32;
#pragma unroll
  for (int it = 0; it < 4; it++) {
    const int r = r8 + it * 8;
    t[r][c] = W[(size_t)(k0 + r) * N + n0 + c];
  }
  __syncthreads();
#pragma unroll
  for (int it = 0; it < 4; it++) {
    const int r = r8 + it * 8;
    WT[(size_t)(n0 + r) * K + k0 + c] = (bf16)t[c][r];
  }
}

// ---- V transpose: qkvb v-part [s][hc+d] -> vT[(hc+d)][s], bf16 -------------
__global__ __launch_bounds__(256) void v_transpose(const bf16* __restrict__ qkvb,
                                                   bf16* __restrict__ vT) {
  __shared__ bf16 t[32][33];
  const int c = threadIdx.x & 31, r8 = threadIdx.x >> 5;
  const int c0 = blockIdx.x * 32;
  const int s0 = blockIdx.y * 32;
#pragma unroll
  for (int it = 0; it < 4; it++) {
    const int r = r8 + it * 8;
    t[r][c] = qkvb[(size_t)(s0 + r) * 1536 + 1024 + c0 + c];
  }
  __syncthreads();
#pragma unroll
  for (int it = 0; it < 4; it++) {
    const int r = r8 + it * 8;
    vT[(size_t)(c0 + r) * S_LEN + s0 + c] = t[c][r];
  }
}

// ------------- shared epilogue math -----------------------------------------
// MODE: 0 = bias -> bf16 out
//       1 = bias + residual(f32) -> f32 out AND bf16 out
//       2 = bias + exact GELU -> bf16 out
//       3 = bias + residual(f32) -> f32 out
template <int MODE>
__device__ __forceinline__ void epilogue_store(float v, const float* res,
                                               float* Cf, bf16* Cb,
                                               size_t row, size_t col, int N) {
  if (MODE == 2) v = 0.5f * v * (1.0f + erff(v * 0.70710678118654752f));
  if (MODE == 1 || MODE == 3) v += res[row * N + col];
  if (MODE == 1 || MODE == 3) Cf[row * N + col] = v;
  if (MODE == 0 || MODE == 1 || MODE == 2) Cb[row * N + col] = (bf16)v;
}

// ---------------- mmA: 64x128 tile, BK=64, double-buffered ------------------
// LDS layout per buffer (matches m97 pattern per 32-k chunk):
//   A: [khalf][row][32], B: [khalf][row][32] — row stride 32 elems (64 B).
template <int MODE>
__global__ __launch_bounds__(256) void mmA_kernel(const bf16* __restrict__ A,
                                                  const bf16* __restrict__ BT,
                                                  const float* __restrict__ bias,
                                                  const float* __restrict__ res,
                                                  float* __restrict__ Cf,
                                                  bf16* __restrict__ Cb,
                                                  int N, int K) {
  __shared__ bf16 As[2][64 * 64];    // 8 KB x2
  __shared__ bf16 Bs[2][128 * 64];   // 16 KB x2
  const int tid = threadIdx.x;
  const int wave = tid >> 6, lane = tid & 63;
  const int lr = lane & 15, kg = lane >> 4;
  const int rowBase = blockIdx.y * 64, colBase = blockIdx.x * 128;

  f32x4 acc[4][2] = {};
  const int niter = K >> 6;

  auto stage = [&](int kk, int buf) {
#pragma unroll
    for (int r = 0; r < 2; ++r) {          // A: 8 x 1KB chunks, 2 per wave
      const int c = wave * 2 + r;
      const int elem = c * 512 + lane * 8;
      const int s = elem >> 11, row = (elem >> 5) & 63, kp = elem & 31;
      const bf16* ga = A + (size_t)(rowBase + row) * K + kk + s * 32 + kp;
      __builtin_amdgcn_global_load_lds(
          (const __attribute__((address_space(1))) void*)ga,
          (__attribute__((address_space(3))) void*)(&As[buf][c * 512]), 16, 0, 0);
    }
#pragma unroll
    for (int r = 0; r < 4; ++r) {          // B: 16 x 1KB chunks, 4 per wave
      const int c = wave * 4 + r;
      const int elem = c * 512 + lane * 8;
      const int s = elem >> 12, row = (elem >> 5) & 127, kp = elem & 31;
      const bf16* gb = BT + (size_t)(colBase + row) * K + kk + s * 32 + kp;
      __builtin_amdgcn_global_load_lds(
          (const __attribute__((address_space(1))) void*)gb,
          (__attribute__((address_space(3))) void*)(&Bs[buf][c * 512]), 16, 0, 0);
    }
  };

  stage(0, 0);
  for (int it = 0; it < niter; ++it) {
    const int cur = it & 1;
    __syncthreads();                        // drains stage(it)'s vmcnt
    if (it + 1 < niter) stage((it + 1) << 6, cur ^ 1);  // prefetch overlaps compute
    const bf16* as = As[cur];
    const bf16* bs = Bs[cur];
#pragma unroll
    for (int s = 0; s < 2; ++s) {
      bf16x8 af[4], bfr[2];
#pragma unroll
      for (int i = 0; i < 4; ++i)
        af[i] = *(const bf16x8*)(as + s * 2048 + (i * 16 + lr) * 32 + kg * 8);
#pragma unroll
      for (int j = 0; j < 2; ++j)
        bfr[j] = *(const bf16x8*)(bs + s * 4096 + (wave * 32 + j * 16 + lr) * 32 + kg * 8);
#pragma unroll
      for (int i = 0; i < 4; ++i)
#pragma unroll
        for (int j = 0; j < 2; ++j)
          acc[i][j] = __builtin_amdgcn_mfma_f32_16x16x32_bf16(af[i], bfr[j],
                                                              acc[i][j], 0, 0, 0);
    }
  }

#pragma unroll
  for (int j = 0; j < 2; ++j) {
    const int col = colBase + wave * 32 + j * 16 + lr;
    const float bs = bias[col];
#pragma unroll
    for (int i = 0; i < 4; ++i)
#pragma unroll
      for (int r = 0; r < 4; ++r)
        epilogue_store<MODE>(acc[i][j][r] + bs, res, Cf, Cb,
                             (size_t)(rowBase + i * 16 + kg * 4 + r),
                             (size_t)col, N);
  }
}

// ---------------- mmB: 32x64 tile, BK=64, double-buffered (N=512 GEMMs) -----
template <int MODE>
__global__ __launch_bounds__(256) void mmB_kernel(const bf16* __restrict__ A,
                                                  const bf16* __restrict__ BT,
                                                  const float* __restrict__ bias,
                                                  const float* __restrict__ res,
                                                  float* __restrict__ Cf,
                                                  bf16* __restrict__ Cb,
                                                  int N, int K) {
  __shared__ bf16 As[2][32 * 64];   // 4 KB x2
  __shared__ bf16 Bs[2][64 * 64];   // 8 KB x2
  const int tid = threadIdx.x;
  const int wave = tid >> 6, lane = tid & 63;
  const int lr = lane & 15, kg = lane >> 4;
  const int rowBase = blockIdx.y * 32, colBase = blockIdx.x * 64;

  f32x4 acc[2] = {};
  const int niter = K >> 6;

  auto stage = [&](int kk, int buf) {
    {                                      // A: 4 x 1KB chunks, 1 per wave
      const int c = wave;
      const int elem = c * 512 + lane * 8;
      const int s = elem >> 10, row = (elem >> 5) & 31, kp = elem & 31;
      const bf16* ga = A + (size_t)(rowBase + row) * K + kk + s * 32 + kp;
      __builtin_amdgcn_global_load_lds(
          (const __attribute__((address_space(1))) void*)ga,
          (__attribute__((address_space(3))) void*)(&As[buf][c * 512]), 16, 0, 0);
    }
#pragma unroll
    for (int r = 0; r < 2; ++r) {          // B: 8 x 1KB chunks, 2 per wave
      const int c = wave * 2 + r;
      const int elem = c * 512 + lane * 8;
      const int s = elem >> 11, row = (elem >> 5) & 63, kp = elem & 31;
      const bf16* gb = BT + (size_t)(colBase + row) * K + kk + s * 32 + kp;
      __builtin_amdgcn_global_load_lds(
          (const __attribute__((address_space(1))) void*)gb,
          (__attribute__((address_space(3))) void*)(&Bs[buf][c * 512]), 16, 0, 0);
    }
  };

  stage(0, 0);
  for (int it = 0; it < niter; ++it) {
    const int cur = it & 1;
    __syncthreads();
    if (it + 1 < niter) stage((it + 1) << 6, cur ^ 1);
    const bf16* as = As[cur];
    const bf16* bs = Bs[cur];
#pragma unroll
    for (int s = 0; s < 2; ++s) {
      bf16x8 af[2], bfr;
#pragma unroll
      for (int i = 0; i < 2; ++i)
        af[i] = *(const bf16x8*)(as + s * 1024 + (i * 16 + lr) * 32 + kg * 8);
      bfr = *(const bf16x8*)(bs + s * 2048 + (wave * 16 + lr) * 32 + kg * 8);
#pragma unroll
      for (int i = 0; i < 2; ++i)
        acc[i] = __builtin_amdgcn_mfma_f32_16x16x32_bf16(af[i], bfr, acc[i], 0, 0, 0);
    }
  }

  {
    const int col = colBase + wave * 16 + lr;
    const float bs = bias[col];
#pragma unroll
    for (int i = 0; i < 2; ++i)
#pragma unroll
      for (int r = 0; r < 4; ++r)
        epilogue_store<MODE>(acc[i][r] + bs, res, Cf, Cb,
                             (size_t)(rowBase + i * 16 + kg * 4 + r),
                             (size_t)col, N);
  }
}

// ---------------- fused MFMA local attention (unchanged, verified) ----------
__global__ __launch_bounds__(256) void attn_fused(const bf16* __restrict__ qkvb,
                                                  const bf16* __restrict__ vT,
                                                  bf16* __restrict__ attnb) {
  __shared__ bf16 Kl[192][72];
  __shared__ bf16 Vt[64][200];
  __shared__ bf16 Ql[64][72];

  const int tid = threadIdx.x;
  const int s0 = blockIdx.x * 64;
  const int hc = blockIdx.y * DHEAD;

  {
    const int row = tid >> 2, c0 = (tid & 3) * 16;
    const bf16* src = qkvb + (size_t)(s0 + row) * 1536 + hc + c0;
    *(bf16x8*)&Ql[row][c0] = *(const bf16x8*)src;
    *(bf16x8*)&Ql[row][c0 + 8] = *(const bf16x8*)(src + 8);
  }
#pragma unroll
  for (int it = 0; it < 3; it++) {
    const int row = it * 64 + (tid >> 2), c0 = (tid & 3) * 16;
    const int p = s0 - 64 + row;
    bf16x8 a, b;
    if (p >= 0 && p < S_LEN) {
      const bf16* src = qkvb + (size_t)p * 1536 + 512 + hc + c0;
      a = *(const bf16x8*)src;
      b = *(const bf16x8*)(src + 8);
    } else {
#pragma unroll
      for (int j = 0; j < 8; j++) { a[j] = (bf16)0.f; b[j] = (bf16)0.f; }
    }
    *(bf16x8*)&Kl[row][c0] = a;
    *(bf16x8*)&Kl[row][c0 + 8] = b;
  }
  {
    const int d = tid >> 2, r0 = (tid & 3) * 48;
    const bf16* src = vT + (size_t)(hc + d) * S_LEN;
#pragma unroll
    for (int i = 0; i < 6; i++) {
      const int p0 = s0 - 64 + r0 + i * 8;
      bf16x8 v;
      if (p0 >= 0 && p0 + 8 <= S_LEN) {
        v = *(const bf16x8*)(src + p0);
      } else {
#pragma unroll
        for (int j = 0; j < 8; j++) {
          const int p = p0 + j;
          v[j] = (p >= 0 && p < S_LEN) ? src[p] : (bf16)0.f;
        }
      }
      *(bf16x8*)&Vt[d][r0 + i * 8] = v;
    }
  }
  __syncthreads();

  const int wv = tid >> 6, lane = tid & 63;
  const int lr = lane & 15, kg = lane >> 4;

  f32x4 c[12] = {};
#pragma unroll
  for (int step = 0; step < 2; step++) {
    const bf16x8 qf = *(const bf16x8*)&Ql[wv * 16 + lr][step * 32 + kg * 8];
#pragma unroll
    for (int t = 0; t < 12; t++) {
      const bf16x8 kf = *(const bf16x8*)&Kl[t * 16 + lr][step * 32 + kg * 8];
      c[t] = __builtin_amdgcn_mfma_f32_16x16x32_bf16(qf, kf, c[t], 0, 0, 0);
    }
  }

  float e[12][4];
  float inv[4];
#pragma unroll
  for (int rr = 0; rr < 4; rr++) {
    const int q = wv * 16 + kg * 4 + rr;
    float m = -1e30f;
#pragma unroll
    for (int t = 0; t < 12; t++) {
      const int col = t * 16 + lr;
      if (col >= q && col <= q + 128) m = fmaxf(m, c[t][rr] * 0.125f);
    }
#pragma unroll
    for (int off = 1; off < 16; off <<= 1) m = fmaxf(m, __shfl_xor(m, off));
    float sum = 0.f;
#pragma unroll
    for (int t = 0; t < 12; t++) {
      const int col = t * 16 + lr;
      const bool valid = (col >= q) && (col <= q + 128);
      const float ev = valid ? __expf(c[t][rr] * 0.125f - m) : 0.f;
      e[t][rr] = ev;
      sum += ev;
    }
#pragma unroll
    for (int off = 1; off < 16; off <<= 1) sum += __shfl_xor(sum, off);
    inv[rr] = 1.f / sum;
  }

  __syncthreads();

  bf16* Pl = (bf16*)Kl + wv * (16 * 200);
#pragma unroll
  for (int rr = 0; rr < 4; rr++)
#pragma unroll
    for (int t = 0; t < 12; t++)
      Pl[(kg * 4 + rr) * 200 + t * 16 + lr] = (bf16)(e[t][rr] * inv[rr]);

  f32x4 o[4] = {};
#pragma unroll
  for (int step = 0; step < 6; step++) {
    const bf16x8 pf = *(const bf16x8*)&Pl[lr * 200 + step * 32 + kg * 8];
#pragma unroll
    for (int jt = 0; jt < 4; jt++) {
      const bf16x8 vf = *(const bf16x8*)&Vt[jt * 16 + lr][step * 32 + kg * 8];
      o[jt] = __builtin_amdgcn_mfma_f32_16x16x32_bf16(pf, vf, o[jt], 0, 0, 0);
    }
  }

#pragma unroll
  for (int jt = 0; jt < 4; jt++)
#pragma unroll
    for (int rr = 0; rr < 4; rr++) {
      const int q = wv * 16 + kg * 4 + rr;
      attnb[(size_t)(s0 + q) * DMODEL + hc + jt * 16 + lr] = (bf16)o[jt][rr];
    }
}

// ---------------- launch ----------------
extern "C" void kernel_launch(void* const* d_in, const int* in_sizes, int n_in,
                              void* d_out, int out_size, void* d_ws, size_t ws_size,
                              hipStream_t stream) {
  const float* x     = (const float*)d_in[0];
  const float* w_qkv = (const float*)d_in[1];
  const float* b_qkv = (const float*)d_in[2];
  const float* w_out = (const float*)d_in[3];
  const float* b_out = (const float*)d_in[4];
  const float* ln_g  = (const float*)d_in[5];
  const float* ln_b  = (const float*)d_in[6];
  const float* w1    = (const float*)d_in[7];
  const float* b1    = (const float*)d_in[8];
  const float* w2    = (const float*)d_in[9];
  const float* b2    = (const float*)d_in[10];
  float* out = (float*)d_out;

  char* w = (char*)d_ws;
  const size_t MB = 1u << 20;
  bf16* xn    = (bf16*)(w + 0);           // [0,2) MB
  bf16* attnb = (bf16*)(w + 0);           // alias xn (dead after QKV)
  bf16* qkvb  = (bf16*)(w + 2 * MB);      // [2,8) MB
  bf16* outb  = (bf16*)(w + 2 * MB);      // alias qkvb (dead after attention)
  bf16* vT    = (bf16*)(w + 8 * MB);      // [8,10) MB
  bf16* h1    = (bf16*)(w + 10 * MB);     // [10,18) MB
  bf16* wqkvT = (bf16*)(w + 18 * MB);     // 1.5 MB
  bf16* woutT = (bf16*)(w + 19 * MB + 512 * 1024);  // 0.5 MB
  bf16* w1T   = (bf16*)(w + 20 * MB);     // 2 MB
  bf16* w2T   = (bf16*)(w + 22 * MB);     // 2 MB

  transpose_all<<<3072, 256, 0, stream>>>(w_qkv, w_out, w1, w2,
                                          wqkvT, woutT, w1T, w2T);
  ln_kernel<<<S_LEN, 256, 0, stream>>>(x, ln_g, ln_b, xn);
  // QKV: [2048,512]@[512,1536] -> bf16; 64x128 tiles -> 384 blocks
  mmA_kernel<0><<<dim3(12, 32), 256, 0, stream>>>(xn, wqkvT, b_qkv, nullptr,
                                                  nullptr, qkvb, 1536, 512);
  v_transpose<<<dim3(16, 64), 256, 0, stream>>>(qkvb, vT);
  attn_fused<<<dim3(32, 8), 256, 0, stream>>>(qkvb, vT, attnb);
  // out-proj + residual(x): 32x64 tiles -> 512 blocks
  mmB_kernel<1><<<dim3(8, 64), 256, 0, stream>>>(attnb, woutT, b_out, x, out,
                                                 outb, 512, 512);
  // FFN1 + GELU: 64x128 tiles -> 512 blocks
  mmA_kernel<2><<<dim3(16, 32), 256, 0, stream>>>(outb, w1T, b1, nullptr,
                                                  nullptr, h1, 2048, 512);
  // FFN2 + residual(out): 32x64 tiles -> 512 blocks (in-place safe)
  mmB_kernel<3><<<dim3(8, 64), 256, 0, stream>>>(h1, w2T, b2, out, out,
                                                 nullptr, 512, 2048);
}

// Round 5
// 141.631 us; speedup vs baseline: 3.9094x; 1.0429x over previous
//
#include <hip/hip_runtime.h>
#include <math.h>

#define S_LEN 2048
#define DMODEL 512
#define NHEAD 8
#define DHEAD 64
#define LN_EPS 1e-5f

typedef __bf16 bf16;
typedef __bf16 bf16x8 __attribute__((ext_vector_type(8)));
typedef __bf16 bf16x4 __attribute__((ext_vector_type(4)));
typedef __bf16 bf16x2 __attribute__((ext_vector_type(2)));
typedef float f32x4 __attribute__((ext_vector_type(4)));

__device__ __forceinline__ float wave_reduce_sum(float x) {
#pragma unroll
  for (int off = 32; off > 0; off >>= 1) x += __shfl_xor(x, off);
  return x;
}

// ---------------- prep: LN (blocks 0..2047) + weight transposes -------------
__global__ __launch_bounds__(256) void prep_kernel(
    const float* __restrict__ x, const float* __restrict__ ln_g,
    const float* __restrict__ ln_b, const float* __restrict__ w_qkv,
    const float* __restrict__ w_out, const float* __restrict__ w1,
    const float* __restrict__ w2, bf16* __restrict__ xn,
    bf16* __restrict__ wqkvT, bf16* __restrict__ woutT,
    bf16* __restrict__ w1T, bf16* __restrict__ w2T) {
  __shared__ float t[32][33];
  int b = blockIdx.x;
  const int tid = threadIdx.x;
  if (b < 2048) {
    // ---- LayerNorm row b ----
    const float2 v = ((const float2*)(x + (size_t)b * DMODEL))[tid];
    float s = v.x + v.y;
    float s2 = v.x * v.x + v.y * v.y;
    s = wave_reduce_sum(s);
    s2 = wave_reduce_sum(s2);
    __shared__ float red[2][4];
    const int wv = tid >> 6, ln = tid & 63;
    if (ln == 0) { red[0][wv] = s; red[1][wv] = s2; }
    __syncthreads();
    s = red[0][0] + red[0][1] + red[0][2] + red[0][3];
    s2 = red[1][0] + red[1][1] + red[1][2] + red[1][3];
    const float mu = s * (1.0f / DMODEL);
    const float var = s2 * (1.0f / DMODEL) - mu * mu;
    const float rs = rsqrtf(var + LN_EPS);
    const float2 gg = ((const float2*)ln_g)[tid];
    const float2 bb = ((const float2*)ln_b)[tid];
    bf16x2 o;
    o[0] = (bf16)((v.x - mu) * rs * gg.x + bb.x);
    o[1] = (bf16)((v.y - mu) * rs * gg.y + bb.y);
    ((bf16x2*)(xn + (size_t)b * DMODEL))[tid] = o;
    return;
  }
  // ---- weight cast+transpose ----
  b -= 2048;
  const float* W; bf16* WT; int K, N, bx, by;
  if (b < 768)       { W = w_qkv; WT = wqkvT; K = 512;  N = 1536; bx = b % 48; by = b / 48; }
  else if (b < 1024) { b -= 768;  W = w_out; WT = woutT; K = 512;  N = 512;  bx = b % 16; by = b / 16; }
  else if (b < 2048) { b -= 1024; W = w1;    WT = w1T;   K = 512;  N = 2048; bx = b % 64; by = b / 64; }
  else               { b -= 2048; W = w2;    WT = w2T;   K = 2048; N = 512;  bx = b % 16; by = b / 16; }
  const int c = tid & 31, r8 = tid >> 5;
  const int n0 = bx * 32, k0 = by * 32;
#pragma unroll
  for (int it = 0; it < 4; it++) {
    const int r = r8 + it * 8;
    t[r][c] = W[(size_t)(k0 + r) * N + n0 + c];
  }
  __syncthreads();
#pragma unroll
  for (int it = 0; it < 4; it++) {
    const int r = r8 + it * 8;
    WT[(size_t)(n0 + r) * K + k0 + c] = (bf16)t[c][r];
  }
}

// ------------- shared epilogue math -----------------------------------------
// MODE: 1 = bias + residual(f32) -> f32 out AND bf16 out
//       2 = bias + exact GELU -> bf16 out
//       3 = bias + residual(f32) -> f32 out
template <int MODE>
__device__ __forceinline__ void epilogue_store(float v, const float* res,
                                               float* Cf, bf16* Cb,
                                               size_t row, size_t col, int N) {
  if (MODE == 2) v = 0.5f * v * (1.0f + erff(v * 0.70710678118654752f));
  if (MODE == 1 || MODE == 3) v += res[row * N + col];
  if (MODE == 1 || MODE == 3) Cf[row * N + col] = v;
  if (MODE == 1 || MODE == 2) Cb[row * N + col] = (bf16)v;
}

// ---------------- mmC: 64x64 tile, BK=64, double-buffered -------------------
// MODE 4 = QKV special: bias -> bf16 qkvb for cols<1024; V cols write vT^T.
// MODE 2 = bias + GELU -> bf16.
template <int MODE>
__global__ __launch_bounds__(256) void mmC_kernel(const bf16* __restrict__ A,
                                                  const bf16* __restrict__ BT,
                                                  const float* __restrict__ bias,
                                                  bf16* __restrict__ Cb,
                                                  bf16* __restrict__ vT,
                                                  int N, int K) {
  __shared__ bf16 As[2][64 * 64];   // 8 KB x2
  __shared__ bf16 Bs[2][64 * 64];   // 8 KB x2
  const int tid = threadIdx.x;
  const int wave = tid >> 6, lane = tid & 63;
  const int lr = lane & 15, kg = lane >> 4;
  const int wm = wave & 1, wn = wave >> 1;
  const int rowBase = blockIdx.y * 64, colBase = blockIdx.x * 64;

  // staging geometry: 8 chunks of 512 elems each for A and B; 2 each per wave
  const bf16* aP[2]; const bf16* bP[2]; int aOff[2], bOff[2];
#pragma unroll
  for (int r = 0; r < 2; ++r) {
    const int c = wave * 2 + r;
    const int elem = c * 512 + lane * 8;
    const int s = elem >> 11, row = (elem >> 5) & 63, kp = elem & 31;
    aP[r] = A + (size_t)(rowBase + row) * K + s * 32 + kp;
    bP[r] = BT + (size_t)(colBase + row) * K + s * 32 + kp;
    aOff[r] = c * 512;
    bOff[r] = c * 512;
  }

  auto stage = [&](int kk, int buf) {
#pragma unroll
    for (int r = 0; r < 2; ++r) {
      __builtin_amdgcn_global_load_lds(
          (const __attribute__((address_space(1))) void*)(aP[r] + kk),
          (__attribute__((address_space(3))) void*)(&As[buf][aOff[r]]), 16, 0, 0);
      __builtin_amdgcn_global_load_lds(
          (const __attribute__((address_space(1))) void*)(bP[r] + kk),
          (__attribute__((address_space(3))) void*)(&Bs[buf][bOff[r]]), 16, 0, 0);
    }
  };

  f32x4 acc[2][2] = {};
  const int niter = K >> 6;

  stage(0, 0);
  for (int it = 0; it < niter; ++it) {
    const int cur = it & 1;
    __syncthreads();
    if (it + 1 < niter) stage((it + 1) << 6, cur ^ 1);
    const bf16* as = As[cur];
    const bf16* bs = Bs[cur];
#pragma unroll
    for (int s = 0; s < 2; ++s) {
      bf16x8 af[2], bfr[2];
#pragma unroll
      for (int i = 0; i < 2; ++i)
        af[i] = *(const bf16x8*)(as + s * 2048 + (wm * 32 + i * 16 + lr) * 32 + kg * 8);
#pragma unroll
      for (int j = 0; j < 2; ++j)
        bfr[j] = *(const bf16x8*)(bs + s * 2048 + (wn * 32 + j * 16 + lr) * 32 + kg * 8);
#pragma unroll
      for (int i = 0; i < 2; ++i)
#pragma unroll
        for (int j = 0; j < 2; ++j)
          acc[i][j] = __builtin_amdgcn_mfma_f32_16x16x32_bf16(af[i], bfr[j],
                                                              acc[i][j], 0, 0, 0);
    }
  }

#pragma unroll
  for (int j = 0; j < 2; ++j) {
    const int col = colBase + wn * 32 + j * 16 + lr;
    const float bs = bias[col];
    if (MODE == 4 && col >= 1024) {
      // V region: write transposed into vT[(col-1024)][row], 4 rows packed
      bf16* dst = vT + (size_t)(col - 1024) * S_LEN;
#pragma unroll
      for (int i = 0; i < 2; ++i) {
        bf16x4 p;
#pragma unroll
        for (int r = 0; r < 4; ++r) p[r] = (bf16)(acc[i][j][r] + bs);
        *(bf16x4*)(dst + rowBase + wm * 32 + i * 16 + kg * 4) = p;
      }
    } else {
#pragma unroll
      for (int i = 0; i < 2; ++i)
#pragma unroll
        for (int r = 0; r < 4; ++r) {
          const size_t row = rowBase + wm * 32 + i * 16 + kg * 4 + r;
          float v = acc[i][j][r] + bs;
          if (MODE == 2) v = 0.5f * v * (1.0f + erff(v * 0.70710678118654752f));
          Cb[row * N + col] = (bf16)v;
        }
    }
  }
}

// ---------------- mmB: 32x64 tile, BK=64, double-buffered (N=512 GEMMs) -----
template <int MODE>
__global__ __launch_bounds__(256) void mmB_kernel(const bf16* __restrict__ A,
                                                  const bf16* __restrict__ BT,
                                                  const float* __restrict__ bias,
                                                  const float* __restrict__ res,
                                                  float* __restrict__ Cf,
                                                  bf16* __restrict__ Cb,
                                                  int N, int K) {
  __shared__ bf16 As[2][32 * 64];   // 4 KB x2
  __shared__ bf16 Bs[2][64 * 64];   // 8 KB x2
  const int tid = threadIdx.x;
  const int wave = tid >> 6, lane = tid & 63;
  const int lr = lane & 15, kg = lane >> 4;
  const int rowBase = blockIdx.y * 32, colBase = blockIdx.x * 64;

  const bf16* aP; const bf16* bP[2]; int aOff, bOff[2];
  {
    const int elem = wave * 512 + lane * 8;
    const int s = elem >> 10, row = (elem >> 5) & 31, kp = elem & 31;
    aP = A + (size_t)(rowBase + row) * K + s * 32 + kp;
    aOff = wave * 512;
  }
#pragma unroll
  for (int r = 0; r < 2; ++r) {
    const int c = wave * 2 + r;
    const int elem = c * 512 + lane * 8;
    const int s = elem >> 11, row = (elem >> 5) & 63, kp = elem & 31;
    bP[r] = BT + (size_t)(colBase + row) * K + s * 32 + kp;
    bOff[r] = c * 512;
  }

  auto stage = [&](int kk, int buf) {
    __builtin_amdgcn_global_load_lds(
        (const __attribute__((address_space(1))) void*)(aP + kk),
        (__attribute__((address_space(3))) void*)(&As[buf][aOff]), 16, 0, 0);
#pragma unroll
    for (int r = 0; r < 2; ++r)
      __builtin_amdgcn_global_load_lds(
          (const __attribute__((address_space(1))) void*)(bP[r] + kk),
          (__attribute__((address_space(3))) void*)(&Bs[buf][bOff[r]]), 16, 0, 0);
  };

  f32x4 acc[2] = {};
  const int niter = K >> 6;

  stage(0, 0);
  for (int it = 0; it < niter; ++it) {
    const int cur = it & 1;
    __syncthreads();
    if (it + 1 < niter) stage((it + 1) << 6, cur ^ 1);
    const bf16* as = As[cur];
    const bf16* bs = Bs[cur];
#pragma unroll
    for (int s = 0; s < 2; ++s) {
      bf16x8 af[2], bfr;
#pragma unroll
      for (int i = 0; i < 2; ++i)
        af[i] = *(const bf16x8*)(as + s * 1024 + (i * 16 + lr) * 32 + kg * 8);
      bfr = *(const bf16x8*)(bs + s * 2048 + (wave * 16 + lr) * 32 + kg * 8);
#pragma unroll
      for (int i = 0; i < 2; ++i)
        acc[i] = __builtin_amdgcn_mfma_f32_16x16x32_bf16(af[i], bfr, acc[i], 0, 0, 0);
    }
  }

  {
    const int col = colBase + wave * 16 + lr;
    const float bs = bias[col];
#pragma unroll
    for (int i = 0; i < 2; ++i)
#pragma unroll
      for (int r = 0; r < 4; ++r)
        epilogue_store<MODE>(acc[i][r] + bs, res, Cf, Cb,
                             (size_t)(rowBase + i * 16 + kg * 4 + r),
                             (size_t)col, N);
  }
}

// ---------------- fused MFMA local attention (unchanged, verified) ----------
__global__ __launch_bounds__(256) void attn_fused(const bf16* __restrict__ qkvb,
                                                  const bf16* __restrict__ vT,
                                                  bf16* __restrict__ attnb) {
  __shared__ bf16 Kl[192][72];
  __shared__ bf16 Vt[64][200];
  __shared__ bf16 Ql[64][72];

  const int tid = threadIdx.x;
  const int s0 = blockIdx.x * 64;
  const int hc = blockIdx.y * DHEAD;

  {
    const int row = tid >> 2, c0 = (tid & 3) * 16;
    const bf16* src = qkvb + (size_t)(s0 + row) * 1536 + hc + c0;
    *(bf16x8*)&Ql[row][c0] = *(const bf16x8*)src;
    *(bf16x8*)&Ql[row][c0 + 8] = *(const bf16x8*)(src + 8);
  }
#pragma unroll
  for (int it = 0; it < 3; it++) {
    const int row = it * 64 + (tid >> 2), c0 = (tid & 3) * 16;
    const int p = s0 - 64 + row;
    bf16x8 a, b;
    if (p >= 0 && p < S_LEN) {
      const bf16* src = qkvb + (size_t)p * 1536 + 512 + hc + c0;
      a = *(const bf16x8*)src;
      b = *(const bf16x8*)(src + 8);
    } else {
#pragma unroll
      for (int j = 0; j < 8; j++) { a[j] = (bf16)0.f; b[j] = (bf16)0.f; }
    }
    *(bf16x8*)&Kl[row][c0] = a;
    *(bf16x8*)&Kl[row][c0 + 8] = b;
  }
  {
    const int d = tid >> 2, r0 = (tid & 3) * 48;
    const bf16* src = vT + (size_t)(hc + d) * S_LEN;
#pragma unroll
    for (int i = 0; i < 6; i++) {
      const int p0 = s0 - 64 + r0 + i * 8;
      bf16x8 v;
      if (p0 >= 0 && p0 + 8 <= S_LEN) {
        v = *(const bf16x8*)(src + p0);
      } else {
#pragma unroll
        for (int j = 0; j < 8; j++) {
          const int p = p0 + j;
          v[j] = (p >= 0 && p < S_LEN) ? src[p] : (bf16)0.f;
        }
      }
      *(bf16x8*)&Vt[d][r0 + i * 8] = v;
    }
  }
  __syncthreads();

  const int wv = tid >> 6, lane = tid & 63;
  const int lr = lane & 15, kg = lane >> 4;

  f32x4 c[12] = {};
#pragma unroll
  for (int step = 0; step < 2; step++) {
    const bf16x8 qf = *(const bf16x8*)&Ql[wv * 16 + lr][step * 32 + kg * 8];
#pragma unroll
    for (int t = 0; t < 12; t++) {
      const bf16x8 kf = *(const bf16x8*)&Kl[t * 16 + lr][step * 32 + kg * 8];
      c[t] = __builtin_amdgcn_mfma_f32_16x16x32_bf16(qf, kf, c[t], 0, 0, 0);
    }
  }

  float e[12][4];
  float inv[4];
#pragma unroll
  for (int rr = 0; rr < 4; rr++) {
    const int q = wv * 16 + kg * 4 + rr;
    float m = -1e30f;
#pragma unroll
    for (int t = 0; t < 12; t++) {
      const int col = t * 16 + lr;
      if (col >= q && col <= q + 128) m = fmaxf(m, c[t][rr] * 0.125f);
    }
#pragma unroll
    for (int off = 1; off < 16; off <<= 1) m = fmaxf(m, __shfl_xor(m, off));
    float sum = 0.f;
#pragma unroll
    for (int t = 0; t < 12; t++) {
      const int col = t * 16 + lr;
      const bool valid = (col >= q) && (col <= q + 128);
      const float ev = valid ? __expf(c[t][rr] * 0.125f - m) : 0.f;
      e[t][rr] = ev;
      sum += ev;
    }
#pragma unroll
    for (int off = 1; off < 16; off <<= 1) sum += __shfl_xor(sum, off);
    inv[rr] = 1.f / sum;
  }

  __syncthreads();

  bf16* Pl = (bf16*)Kl + wv * (16 * 200);
#pragma unroll
  for (int rr = 0; rr < 4; rr++)
#pragma unroll
    for (int t = 0; t < 12; t++)
      Pl[(kg * 4 + rr) * 200 + t * 16 + lr] = (bf16)(e[t][rr] * inv[rr]);

  f32x4 o[4] = {};
#pragma unroll
  for (int step = 0; step < 6; step++) {
    const bf16x8 pf = *(const bf16x8*)&Pl[lr * 200 + step * 32 + kg * 8];
#pragma unroll
    for (int jt = 0; jt < 4; jt++) {
      const bf16x8 vf = *(const bf16x8*)&Vt[jt * 16 + lr][step * 32 + kg * 8];
      o[jt] = __builtin_amdgcn_mfma_f32_16x16x32_bf16(pf, vf, o[jt], 0, 0, 0);
    }
  }

#pragma unroll
  for (int jt = 0; jt < 4; jt++)
#pragma unroll
    for (int rr = 0; rr < 4; rr++) {
      const int q = wv * 16 + kg * 4 + rr;
      attnb[(size_t)(s0 + q) * DMODEL + hc + jt * 16 + lr] = (bf16)o[jt][rr];
    }
}

// ---------------- launch ----------------
extern "C" void kernel_launch(void* const* d_in, const int* in_sizes, int n_in,
                              void* d_out, int out_size, void* d_ws, size_t ws_size,
                              hipStream_t stream) {
  const float* x     = (const float*)d_in[0];
  const float* w_qkv = (const float*)d_in[1];
  const float* b_qkv = (const float*)d_in[2];
  const float* w_out = (const float*)d_in[3];
  const float* b_out = (const float*)d_in[4];
  const float* ln_g  = (const float*)d_in[5];
  const float* ln_b  = (const float*)d_in[6];
  const float* w1    = (const float*)d_in[7];
  const float* b1    = (const float*)d_in[8];
  const float* w2    = (const float*)d_in[9];
  const float* b2    = (const float*)d_in[10];
  float* out = (float*)d_out;

  char* w = (char*)d_ws;
  const size_t MB = 1u << 20;
  bf16* xn    = (bf16*)(w + 0);           // [0,2) MB
  bf16* attnb = (bf16*)(w + 0);           // alias xn (dead after QKV)
  bf16* qkvb  = (bf16*)(w + 2 * MB);      // [2,8) MB
  bf16* outb  = (bf16*)(w + 2 * MB);      // alias qkvb (dead after attention)
  bf16* vT    = (bf16*)(w + 8 * MB);      // [8,10) MB
  bf16* h1    = (bf16*)(w + 10 * MB);     // [10,18) MB
  bf16* wqkvT = (bf16*)(w + 18 * MB);     // 1.5 MB
  bf16* woutT = (bf16*)(w + 19 * MB + 512 * 1024);  // 0.5 MB
  bf16* w1T   = (bf16*)(w + 20 * MB);     // 2 MB
  bf16* w2T   = (bf16*)(w + 22 * MB);     // 2 MB

  // prep: LN (2048 blocks) + all weight transposes (3072 blocks)
  prep_kernel<<<5120, 256, 0, stream>>>(x, ln_g, ln_b, w_qkv, w_out, w1, w2,
                                        xn, wqkvT, woutT, w1T, w2T);
  // QKV: [2048,512]@[512,1536] -> bf16 qkvb; V cols -> vT transposed.
  // 64x64 tiles -> 768 blocks (3/CU).
  mmC_kernel<4><<<dim3(24, 32), 256, 0, stream>>>(xn, wqkvT, b_qkv, qkvb, vT,
                                                  1536, 512);
  attn_fused<<<dim3(32, 8), 256, 0, stream>>>(qkvb, vT, attnb);
  // out-proj + residual(x): 32x64 tiles -> 512 blocks
  mmB_kernel<1><<<dim3(8, 64), 256, 0, stream>>>(attnb, woutT, b_out, x, out,
                                                 outb, 512, 512);
  // FFN1 + GELU: 64x64 tiles -> 1024 blocks (4/CU)
  mmC_kernel<2><<<dim3(32, 32), 256, 0, stream>>>(outb, w1T, b1, h1, nullptr,
                                                  2048, 512);
  // FFN2 + residual(out): 32x64 tiles -> 512 blocks (in-place safe)
  mmB_kernel<3><<<dim3(8, 64), 256, 0, stream>>>(h1, w2T, b2, out, out,
                                                 nullptr, 512, 2048);
}